// Round 11
// baseline (213.888 us; speedup 1.0000x reference)
//
#include <hip/hip_runtime.h>
#include <stdint.h>

#define DIM 256
#define NROWS 8192
#define KTOT 8192
#define KSPLIT 8
#define KSZ 1024  // k per split

typedef unsigned short u16;
typedef short bf16x8 __attribute__((ext_vector_type(8)));
typedef float f32x4 __attribute__((ext_vector_type(4)));

__device__ __forceinline__ u16 f2bf(float x) {
  uint32_t u = __float_as_uint(x);
  u = (u + 0x7FFFu + ((u >> 16) & 1u)) >> 16;
  return (u16)u;
}

__device__ __forceinline__ float wsum(float v) {
  v += __shfl_xor(v, 32, 64);
  v += __shfl_xor(v, 16, 64);
  v += __shfl_xor(v, 8, 64);
  v += __shfl_xor(v, 4, 64);
  v += __shfl_xor(v, 2, 64);
  v += __shfl_xor(v, 1, 64);
  return v;
}

__device__ __forceinline__ float artanh_c(float x) {
  const float lim = 1.0f - 1e-7f;
  x = fminf(fmaxf(x, -lim), lim);
  return 0.5f * (log1pf(x) - log1pf(-x));
}

// ---------------- K1: mx = x @ W^T  (fp32, 64x64 tiles) ----------------
__global__ __launch_bounds__(256)
void hgcn_k1(const float* __restrict__ x, const float* __restrict__ w,
             float* __restrict__ mx) {
  __shared__ float xs_t[32][64];
  __shared__ float ws_t[32][64];
  int t = threadIdx.x;
  int tx = t & 15, ty = t >> 4;
  int bi = blockIdx.x, bj = blockIdx.y;
  int lr = t >> 2, lc = (t & 3) * 8;
  const float* xp = x + (size_t)(bi * 64 + lr) * DIM + lc;
  const float* wp = w + (size_t)(bj * 64 + lr) * DIM + lc;
  float acc[4][4] = {};
  for (int kb = 0; kb < DIM; kb += 32) {
    float4 a0 = *(const float4*)(xp + kb);
    float4 a1 = *(const float4*)(xp + kb + 4);
    float4 b0 = *(const float4*)(wp + kb);
    float4 b1 = *(const float4*)(wp + kb + 4);
    __syncthreads();
    xs_t[lc + 0][lr] = a0.x; xs_t[lc + 1][lr] = a0.y;
    xs_t[lc + 2][lr] = a0.z; xs_t[lc + 3][lr] = a0.w;
    xs_t[lc + 4][lr] = a1.x; xs_t[lc + 5][lr] = a1.y;
    xs_t[lc + 6][lr] = a1.z; xs_t[lc + 7][lr] = a1.w;
    ws_t[lc + 0][lr] = b0.x; ws_t[lc + 1][lr] = b0.y;
    ws_t[lc + 2][lr] = b0.z; ws_t[lc + 3][lr] = b0.w;
    ws_t[lc + 4][lr] = b1.x; ws_t[lc + 5][lr] = b1.y;
    ws_t[lc + 6][lr] = b1.z; ws_t[lc + 7][lr] = b1.w;
    __syncthreads();
#pragma unroll
    for (int k = 0; k < 32; ++k) {
      float4 xv = *(const float4*)&xs_t[k][ty * 4];
      float4 wv = *(const float4*)&ws_t[k][tx * 4];
      float xr[4] = {xv.x, xv.y, xv.z, xv.w};
      float wr[4] = {wv.x, wv.y, wv.z, wv.w};
#pragma unroll
      for (int ii = 0; ii < 4; ++ii)
#pragma unroll
        for (int jj = 0; jj < 4; ++jj)
          acc[ii][jj] += xr[ii] * wr[jj];
    }
  }
#pragma unroll
  for (int ii = 0; ii < 4; ++ii) {
    float4 o = {acc[ii][0], acc[ii][1], acc[ii][2], acc[ii][3]};
    *(float4*)(mx + (size_t)(bi * 64 + ty * 4 + ii) * DIM + bj * 64 + tx * 4) = o;
  }
}

// ------- K2: hyperbolic chain #1 -> xtTp[kblk 128][256 n][64 k] bf16, swizzle baked -------
__global__ __launch_bounds__(256)
void hgcn_k2(const float* __restrict__ x, const float* __restrict__ mx,
             const float* __restrict__ bias, u16* __restrict__ xtTp) {
  __shared__ u16 xl[64][256];
  const float maxn = 1.0f - 1e-5f;
  int t = threadIdx.x;
  int wave = t >> 6, lane = t & 63;
  int c0 = lane * 4;

  float4 b4 = *(const float4*)(bias + c0);
  float bn2 = wsum(b4.x * b4.x + b4.y * b4.y + b4.z * b4.z + b4.w * b4.w);
  float bn = fmaxf(sqrtf(bn2), 1e-15f);
  float sb = tanhf(bn) / bn;
  float hbx = b4.x * sb, hby = b4.y * sb, hbz = b4.z * sb, hbw = b4.w * sb;
  float ebn2 = wsum(hbx * hbx + hby * hby + hbz * hbz + hbw * hbw);
  float ebn = fmaxf(sqrtf(ebn2), 1e-15f);
  float sp = ebn > maxn ? maxn / ebn : 1.0f;
  hbx *= sp; hby *= sp; hbz *= sp; hbw *= sp;
  float y2 = (ebn * sp) * (ebn * sp);

  for (int rr = 0; rr < 16; ++rr) {
    int iloc = wave * 16 + rr;
    size_t row = (size_t)blockIdx.x * 64 + iloc;
    float4 xv = *(const float4*)(x + row * DIM + c0);
    float4 mv = *(const float4*)(mx + row * DIM + c0);
    float xn2 = wsum(xv.x * xv.x + xv.y * xv.y + xv.z * xv.z + xv.w * xv.w);
    float mxn2 = wsum(mv.x * mv.x + mv.y * mv.y + mv.z * mv.z + mv.w * mv.w);
    int zloc = (mv.x == 0.0f) && (mv.y == 0.0f) && (mv.z == 0.0f) && (mv.w == 0.0f);
    int zrow = __all(zloc);
    float xn = fmaxf(sqrtf(xn2), 1e-15f);
    float mxn = fmaxf(sqrtf(mxn2), 1e-15f);
    float rfac = tanhf(mxn / xn * artanh_c(xn)) / mxn;
    if (zrow) rfac = 0.0f;
    float hx = mv.x * rfac, hy = mv.y * rfac, hz = mv.z * rfac, hw = mv.w * rfac;
    float hn = fmaxf(fabsf(rfac) * mxn, 1e-15f);
    float s1 = hn > maxn ? maxn / hn : 1.0f;
    hx *= s1; hy *= s1; hz *= s1; hw *= s1;
    float x2 = (hn * s1) * (hn * s1);
    float xy = wsum(hx * hbx + hy * hby + hz * hbz + hw * hbw);
    float ca = 1.0f + 2.0f * xy + y2;
    float cb = 1.0f - x2;
    float den = 1.0f + 2.0f * xy + x2 * y2;
    float inv = 1.0f / fmaxf(den, 1e-15f);
    float ox = (ca * hx + cb * hbx) * inv;
    float oy = (ca * hy + cb * hby) * inv;
    float oz = (ca * hz + cb * hbz) * inv;
    float ow = (ca * hw + cb * hbw) * inv;
    float on2 = wsum(ox * ox + oy * oy + oz * oz + ow * ow);
    float on = fmaxf(sqrtf(on2), 1e-15f);
    float s2 = on > maxn ? maxn / on : 1.0f;
    ox *= s2; oy *= s2; oz *= s2; ow *= s2;
    float pn = fmaxf(on * s2, 1e-15f);
    float lf = artanh_c(pn) / pn;
    u16 tmp[4] = {f2bf(ox * lf), f2bf(oy * lf), f2bf(oz * lf), f2bf(ow * lf)};
    *(uint2*)&xl[iloc][c0] = *(const uint2*)tmp;
  }
  __syncthreads();
  int c = t;  // feature row n
  size_t ob = (size_t)blockIdx.x * 16384 + (size_t)c * 64;
  for (int q = 0; q < 8; ++q) {
    u16 tmp[8];
#pragma unroll
    for (int i = 0; i < 8; ++i) tmp[i] = xl[q * 8 + i][c];
    *(uint4*)(xtTp + ob + (size_t)((q ^ (c & 7)) * 8)) = *(const uint4*)tmp;
  }
}

// ------- K3: fused, all-contiguous. BM=32, BK=1024, ksplit=8 (XCD-aligned). -------
#define K3_WAITV(N) { asm volatile("s_waitcnt vmcnt(" #N ")" ::: "memory"); __builtin_amdgcn_sched_barrier(0); }

// full 32KB tile = 32 x 1KB instructions; 4 waves -> 8 per wave
__device__ __forceinline__ void k3_issueA(const u16* __restrict__ src, u16* __restrict__ dst,
                                          int wave, int lane) {
#pragma unroll
  for (int jj = 0; jj < 8; ++jj) {
    int j = wave * 8 + jj;
    __builtin_amdgcn_global_load_lds(
        (const __attribute__((address_space(1))) void*)(src + j * 512 + lane * 8),
        (__attribute__((address_space(3))) void*)(dst + j * 512), 16, 0, 0);
  }
}

__device__ __forceinline__ void k3_compute(const u16* __restrict__ lA, const u16* __restrict__ lB,
                                           f32x4 (&acc)[4][2], int s, int n0, int l15, int l4) {
  __builtin_amdgcn_s_setprio(1);
#pragma unroll
  for (int kc2 = 0; kc2 < 2; ++kc2) {
    bf16x8 a[4], b[2];
#pragma unroll
    for (int mi = 0; mi < 2; ++mi) {
      int r = mi * 16 + l15;
      int c = (s * 2 + kc2) * 4 + l4;                     // 0..127 within 1024-k row
      int sc = (c & ~7) | ((c & 7) ^ (r & 7));
      b[mi] = *(const bf16x8*)((const char*)lB + (size_t)r * 2048 + sc * 16);
    }
#pragma unroll
    for (int ni = 0; ni < 4; ++ni) {
      int rn = n0 + ni * 16 + l15;
      int ca = (kc2 * 4 + l4) ^ (rn & 7);                 // baked swizzle in xtTp
      a[ni] = *(const bf16x8*)(lA + (size_t)rn * 64 + ca * 8);
    }
#pragma unroll
    for (int ni = 0; ni < 4; ++ni)
#pragma unroll
      for (int mi = 0; mi < 2; ++mi)
        acc[ni][mi] = __builtin_amdgcn_mfma_f32_16x16x32_bf16(a[ni], b[mi], acc[ni][mi], 0, 0, 0);
  }
  __builtin_amdgcn_s_setprio(0);
}

__global__ __launch_bounds__(256, 1)
void hgcn_k3(const float* __restrict__ adj, const u16* __restrict__ xtTp,
             float* __restrict__ pbase) {
  __shared__ u16 lB[32 * 1024];      // 64KB: row r (2KB), 16B-chunk c at (c&~7)|((c&7)^(r&7))
  __shared__ u16 lA[3][256 * 64];    // 3 x 32KB ring
  int t = threadIdx.x;
  int wave = t >> 6, lane = t & 63;
  int l15 = lane & 15, l4 = lane >> 4;
  int bid = blockIdx.x;
  int split = bid & 7;               // one split per XCD -> 512KB A-slice L2-resident
  int mt = bid >> 3;                 // 0..255
  int m0 = mt * 32;
  int kbase = split * KSZ;
  float* outp = pbase + (size_t)split * ((size_t)NROWS * DIM);
  int n0 = wave * 64;

  // ---- stage B: 32 rows x 4KB contiguous fp32, 8-deep reg pipeline ----
  {
    const float* base = adj + (size_t)(m0 + wave * 8) * KTOT + kbase;
    f32x4 L[8];
#pragma unroll
    for (int i = 0; i < 8; ++i) {
      int row = i >> 2, j = i & 3;
      L[i] = __builtin_nontemporal_load(
          (const f32x4*)(base + (size_t)row * KTOT + j * 256 + lane * 4));
    }
#pragma unroll
    for (int i = 0; i < 32; ++i) {
      f32x4 v = L[i & 7];
      if (i + 8 < 32) {
        int row = (i + 8) >> 2, j = (i + 8) & 3;
        L[i & 7] = __builtin_nontemporal_load(
            (const f32x4*)(base + (size_t)row * KTOT + j * 256 + lane * 4));
      }
      uint32_t w0, w1;
      asm("v_cvt_pk_bf16_f32 %0, %1, %2" : "=v"(w0) : "v"(v[0]), "v"(v[1]));
      asm("v_cvt_pk_bf16_f32 %0, %1, %2" : "=v"(w1) : "v"(v[2]), "v"(v[3]));
      int r = wave * 8 + (i >> 2);
      int c = (i & 3) * 32 + (lane >> 1);
      int sc = (c & ~7) | ((c & 7) ^ (r & 7));
      uint2 d = {w0, w1};
      *(uint2*)((char*)lB + (size_t)r * 2048 + sc * 16 + (lane & 1) * 8) = d;
    }
  }
  asm volatile("s_waitcnt lgkmcnt(0)" ::: "memory");
  __builtin_amdgcn_s_barrier();      // lB staged for all waves

  const u16* aBase = xtTp + (size_t)(split * 16) * 16384;

  f32x4 acc[4][2];
#pragma unroll
  for (int i = 0; i < 4; ++i)
#pragma unroll
    for (int j = 0; j < 2; ++j)
      acc[i][j] = (f32x4){0.f, 0.f, 0.f, 0.f};

  // prologue: issue A-tiles 0,1 (32 gloads each; this wave's share = 8 each)
  k3_issueA(aBase, lA[0], wave, lane);
  k3_issueA(aBase + 16384, lA[1], wave, lane);

  for (int s = 0; s < 14; ++s) {
    K3_WAITV(8);                          // tile s landed (own share)
    __builtin_amdgcn_s_barrier();         // all waves: tile s complete, compute(s-1) retired
    k3_issueA(aBase + (size_t)(s + 2) * 16384, lA[(s + 2) % 3], wave, lane);
    k3_compute(lA[s % 3], lB, acc, s, n0, l15, l4);
  }
  K3_WAITV(8);
  __builtin_amdgcn_s_barrier();
  k3_compute(lA[14 % 3], lB, acc, 14, n0, l15, l4);
  K3_WAITV(0);
  __builtin_amdgcn_s_barrier();
  k3_compute(lA[15 % 3], lB, acc, 15, n0, l15, l4);

  // epilogue: D[n][m] -> partial[m][n]  (mapping verified r2-r9)
#pragma unroll
  for (int ni = 0; ni < 4; ++ni)
#pragma unroll
    for (int mi = 0; mi < 2; ++mi) {
      int n = n0 + ni * 16 + l4 * 4;
      int m = m0 + mi * 16 + l15;
      *(f32x4*)(outp + (size_t)m * DIM + n) = acc[ni][mi];
    }
}

// ---------------- K4: sum 8 partials + hyperbolic chain #2 -> d_out ----------------
__global__ __launch_bounds__(256)
void hgcn_k4(const float* __restrict__ pbase, size_t pstride,
             float* __restrict__ out) {
  const float maxn = 1.0f - 1e-5f;
  int t = threadIdx.x;
  int wave = t >> 6, lane = t & 63;
  size_t row = (size_t)blockIdx.x * 4 + wave;
  int c0 = lane * 4;
  size_t off = row * DIM + c0;
  float sx = 0.f, sy = 0.f, sz = 0.f, sw = 0.f;
#pragma unroll
  for (int i = 0; i < KSPLIT; ++i) {
    float4 v = *(const float4*)(pbase + (size_t)i * pstride + off);
    sx += v.x; sy += v.y; sz += v.z; sw += v.w;
  }
  float un2 = wsum(sx * sx + sy * sy + sz * sz + sw * sw);
  float un = fmaxf(sqrtf(un2), 1e-15f);
  float t1 = tanhf(un) / un;
  float hx = sx * t1, hy = sy * t1, hz = sz * t1, hw = sw * t1;
  float hn = fmaxf(fabsf(t1) * un, 1e-15f);
  float s1 = hn > maxn ? maxn / hn : 1.0f;
  hx *= s1; hy *= s1; hz *= s1; hw *= s1;
  float pn = fmaxf(hn * s1, 1e-15f);
  float lf = artanh_c(pn) / pn;
  float rx = fmaxf(hx * lf, 0.0f), ry = fmaxf(hy * lf, 0.0f);
  float rz = fmaxf(hz * lf, 0.0f), rw = fmaxf(hw * lf, 0.0f);
  float rn2 = wsum(rx * rx + ry * ry + rz * rz + rw * rw);
  float rn = fmaxf(sqrtf(rn2), 1e-15f);
  float t2 = tanhf(rn) / rn;
  float ox = rx * t2, oy = ry * t2, oz = rz * t2, ow = rw * t2;
  float on = fmaxf(fabsf(t2) * rn, 1e-15f);
  float s3 = on > maxn ? maxn / on : 1.0f;
  float4 o = {ox * s3, oy * s3, oz * s3, ow * s3};
  *(float4*)(out + off) = o;
}

extern "C" void kernel_launch(void* const* d_in, const int* in_sizes, int n_in,
                              void* d_out, int out_size, void* d_ws, size_t ws_size,
                              hipStream_t stream) {
  const float* x = (const float*)d_in[0];
  const float* adj = (const float*)d_in[1];
  const float* wgt = (const float*)d_in[2];
  const float* bias = (const float*)d_in[3];
  float* out = (float*)d_out;
  char* ws = (char*)d_ws;
  float* mx = (float*)ws;                         // [0, 8MB)
  u16* xtTp = (u16*)(ws + ((size_t)8 << 20));     // [8, 12MB)
  float* pbase = (float*)(ws + ((size_t)12 << 20)); // [12, 76MB): 8 partials x 8MB

  hipLaunchKernelGGL(hgcn_k1, dim3(128, 4), dim3(256), 0, stream, x, wgt, mx);
  hipLaunchKernelGGL(hgcn_k2, dim3(128), dim3(256), 0, stream, x, mx, bias, xtTp);
  hipLaunchKernelGGL(hgcn_k3, dim3(2048), dim3(256), 0, stream, adj, xtTp, pbase);
  hipLaunchKernelGGL(hgcn_k4, dim3(2048), dim3(256), 0, stream,
                     pbase, (size_t)NROWS * DIM, out);
}

// Round 12
// 176.176 us; speedup vs baseline: 1.2141x; 1.2141x over previous
//
#include <hip/hip_runtime.h>
#include <stdint.h>

#define DIM 256
#define NROWS 8192
#define KTOT 8192
#define KSPLIT 8
#define KSZ 1024  // k per split

typedef unsigned short u16;
typedef short bf16x8 __attribute__((ext_vector_type(8)));
typedef float f32x4 __attribute__((ext_vector_type(4)));

__device__ __forceinline__ u16 f2bf(float x) {
  uint32_t u = __float_as_uint(x);
  u = (u + 0x7FFFu + ((u >> 16) & 1u)) >> 16;
  return (u16)u;
}

__device__ __forceinline__ float wsum(float v) {
  v += __shfl_xor(v, 32, 64);
  v += __shfl_xor(v, 16, 64);
  v += __shfl_xor(v, 8, 64);
  v += __shfl_xor(v, 4, 64);
  v += __shfl_xor(v, 2, 64);
  v += __shfl_xor(v, 1, 64);
  return v;
}

__device__ __forceinline__ float artanh_c(float x) {
  const float lim = 1.0f - 1e-7f;
  x = fminf(fmaxf(x, -lim), lim);
  return 0.5f * (log1pf(x) - log1pf(-x));
}

// ---------------- K1: mx = x @ W^T  (fp32, 64x64 tiles) ----------------
__global__ __launch_bounds__(256)
void hgcn_k1(const float* __restrict__ x, const float* __restrict__ w,
             float* __restrict__ mx) {
  __shared__ float xs_t[32][64];
  __shared__ float ws_t[32][64];
  int t = threadIdx.x;
  int tx = t & 15, ty = t >> 4;
  int bi = blockIdx.x, bj = blockIdx.y;
  int lr = t >> 2, lc = (t & 3) * 8;
  const float* xp = x + (size_t)(bi * 64 + lr) * DIM + lc;
  const float* wp = w + (size_t)(bj * 64 + lr) * DIM + lc;
  float acc[4][4] = {};
  for (int kb = 0; kb < DIM; kb += 32) {
    float4 a0 = *(const float4*)(xp + kb);
    float4 a1 = *(const float4*)(xp + kb + 4);
    float4 b0 = *(const float4*)(wp + kb);
    float4 b1 = *(const float4*)(wp + kb + 4);
    __syncthreads();
    xs_t[lc + 0][lr] = a0.x; xs_t[lc + 1][lr] = a0.y;
    xs_t[lc + 2][lr] = a0.z; xs_t[lc + 3][lr] = a0.w;
    xs_t[lc + 4][lr] = a1.x; xs_t[lc + 5][lr] = a1.y;
    xs_t[lc + 6][lr] = a1.z; xs_t[lc + 7][lr] = a1.w;
    ws_t[lc + 0][lr] = b0.x; ws_t[lc + 1][lr] = b0.y;
    ws_t[lc + 2][lr] = b0.z; ws_t[lc + 3][lr] = b0.w;
    ws_t[lc + 4][lr] = b1.x; ws_t[lc + 5][lr] = b1.y;
    ws_t[lc + 6][lr] = b1.z; ws_t[lc + 7][lr] = b1.w;
    __syncthreads();
#pragma unroll
    for (int k = 0; k < 32; ++k) {
      float4 xv = *(const float4*)&xs_t[k][ty * 4];
      float4 wv = *(const float4*)&ws_t[k][tx * 4];
      float xr[4] = {xv.x, xv.y, xv.z, xv.w};
      float wr[4] = {wv.x, wv.y, wv.z, wv.w};
#pragma unroll
      for (int ii = 0; ii < 4; ++ii)
#pragma unroll
        for (int jj = 0; jj < 4; ++jj)
          acc[ii][jj] += xr[ii] * wr[jj];
    }
  }
#pragma unroll
  for (int ii = 0; ii < 4; ++ii) {
    float4 o = {acc[ii][0], acc[ii][1], acc[ii][2], acc[ii][3]};
    *(float4*)(mx + (size_t)(bi * 64 + ty * 4 + ii) * DIM + bj * 64 + tx * 4) = o;
  }
}

// ------- K2: hyperbolic chain #1 -> xtTp[kblk 128][256 n][64 k] bf16, swizzle baked -------
__global__ __launch_bounds__(256)
void hgcn_k2(const float* __restrict__ x, const float* __restrict__ mx,
             const float* __restrict__ bias, u16* __restrict__ xtTp) {
  __shared__ u16 xl[64][256];
  const float maxn = 1.0f - 1e-5f;
  int t = threadIdx.x;
  int wave = t >> 6, lane = t & 63;
  int c0 = lane * 4;

  float4 b4 = *(const float4*)(bias + c0);
  float bn2 = wsum(b4.x * b4.x + b4.y * b4.y + b4.z * b4.z + b4.w * b4.w);
  float bn = fmaxf(sqrtf(bn2), 1e-15f);
  float sb = tanhf(bn) / bn;
  float hbx = b4.x * sb, hby = b4.y * sb, hbz = b4.z * sb, hbw = b4.w * sb;
  float ebn2 = wsum(hbx * hbx + hby * hby + hbz * hbz + hbw * hbw);
  float ebn = fmaxf(sqrtf(ebn2), 1e-15f);
  float sp = ebn > maxn ? maxn / ebn : 1.0f;
  hbx *= sp; hby *= sp; hbz *= sp; hbw *= sp;
  float y2 = (ebn * sp) * (ebn * sp);

  for (int rr = 0; rr < 16; ++rr) {
    int iloc = wave * 16 + rr;
    size_t row = (size_t)blockIdx.x * 64 + iloc;
    float4 xv = *(const float4*)(x + row * DIM + c0);
    float4 mv = *(const float4*)(mx + row * DIM + c0);
    float xn2 = wsum(xv.x * xv.x + xv.y * xv.y + xv.z * xv.z + xv.w * xv.w);
    float mxn2 = wsum(mv.x * mv.x + mv.y * mv.y + mv.z * mv.z + mv.w * mv.w);
    int zloc = (mv.x == 0.0f) && (mv.y == 0.0f) && (mv.z == 0.0f) && (mv.w == 0.0f);
    int zrow = __all(zloc);
    float xn = fmaxf(sqrtf(xn2), 1e-15f);
    float mxn = fmaxf(sqrtf(mxn2), 1e-15f);
    float rfac = tanhf(mxn / xn * artanh_c(xn)) / mxn;
    if (zrow) rfac = 0.0f;
    float hx = mv.x * rfac, hy = mv.y * rfac, hz = mv.z * rfac, hw = mv.w * rfac;
    float hn = fmaxf(fabsf(rfac) * mxn, 1e-15f);
    float s1 = hn > maxn ? maxn / hn : 1.0f;
    hx *= s1; hy *= s1; hz *= s1; hw *= s1;
    float x2 = (hn * s1) * (hn * s1);
    float xy = wsum(hx * hbx + hy * hby + hz * hbz + hw * hbw);
    float ca = 1.0f + 2.0f * xy + y2;
    float cb = 1.0f - x2;
    float den = 1.0f + 2.0f * xy + x2 * y2;
    float inv = 1.0f / fmaxf(den, 1e-15f);
    float ox = (ca * hx + cb * hbx) * inv;
    float oy = (ca * hy + cb * hby) * inv;
    float oz = (ca * hz + cb * hbz) * inv;
    float ow = (ca * hw + cb * hbw) * inv;
    float on2 = wsum(ox * ox + oy * oy + oz * oz + ow * ow);
    float on = fmaxf(sqrtf(on2), 1e-15f);
    float s2 = on > maxn ? maxn / on : 1.0f;
    ox *= s2; oy *= s2; oz *= s2; ow *= s2;
    float pn = fmaxf(on * s2, 1e-15f);
    float lf = artanh_c(pn) / pn;
    u16 tmp[4] = {f2bf(ox * lf), f2bf(oy * lf), f2bf(oz * lf), f2bf(ow * lf)};
    *(uint2*)&xl[iloc][c0] = *(const uint2*)tmp;
  }
  __syncthreads();
  int c = t;  // feature row n
  size_t ob = (size_t)blockIdx.x * 16384 + (size_t)c * 64;
  for (int q = 0; q < 8; ++q) {
    u16 tmp[8];
#pragma unroll
    for (int i = 0; i < 8; ++i) tmp[i] = xl[q * 8 + i][c];
    *(uint4*)(xtTp + ob + (size_t)((q ^ (c & 7)) * 8)) = *(const uint4*)tmp;
  }
}

// ------- K3: BM=256, BN=256, BK=64x16, KSPLIT=8, counted vmcnt, 2 barriers/body -------
#define K3_WAITV(N) { asm volatile("s_waitcnt vmcnt(" #N ")" ::: "memory"); __builtin_amdgcn_sched_barrier(0); }
#define K3_LGKM0    { asm volatile("s_waitcnt lgkmcnt(0)" ::: "memory"); __builtin_amdgcn_sched_barrier(0); }

struct B8 { float4 v[8]; };

// A-tile 32KB = 32 x 1KB instructions; 8 waves -> 4 per wave
__device__ __forceinline__ void k3_issueA(const u16* __restrict__ src, u16* __restrict__ dst,
                                          int wave, int lane) {
#pragma unroll
  for (int jj = 0; jj < 4; ++jj) {
    int j = wave * 4 + jj;
    __builtin_amdgcn_global_load_lds(
        (const __attribute__((address_space(1))) void*)(src + j * 512 + lane * 8),
        (__attribute__((address_space(3))) void*)(dst + j * 512), 16, 0, 0);
  }
}

__device__ __forceinline__ void k3_loadB(const float* __restrict__ ap, B8& r) {
#pragma unroll
  for (int i = 0; i < 8; ++i) r.v[i] = ((const float4*)ap)[i];
}

// thread covers row rowB, floats [cq*32, cq*32+32) -> 4 swizzled 16B chunks
__device__ __forceinline__ void k3_writeB(u16* __restrict__ bbuf, int rowB, int cq, const B8& r) {
#pragma unroll
  for (int j = 0; j < 4; ++j) {
    float4 a = r.v[2 * j], b = r.v[2 * j + 1];
    uint32_t w0, w1, w2, w3;
    asm("v_cvt_pk_bf16_f32 %0, %1, %2" : "=v"(w0) : "v"(a.x), "v"(a.y));
    asm("v_cvt_pk_bf16_f32 %0, %1, %2" : "=v"(w1) : "v"(a.z), "v"(a.w));
    asm("v_cvt_pk_bf16_f32 %0, %1, %2" : "=v"(w2) : "v"(b.x), "v"(b.y));
    asm("v_cvt_pk_bf16_f32 %0, %1, %2" : "=v"(w3) : "v"(b.z), "v"(b.w));
    int c = cq * 4 + j;
    int sc = c ^ (rowB & 7);
    uint4 d = {w0, w1, w2, w3};
    *(uint4*)((char*)bbuf + (size_t)rowB * 128 + sc * 16) = d;
  }
}

__device__ __forceinline__ void k3_compute(const u16* __restrict__ lA, const u16* __restrict__ lB,
                                           f32x4 (&acc)[4][8], int wm, int wn, int l15, int l4) {
  __builtin_amdgcn_s_setprio(1);
#pragma unroll
  for (int kc = 0; kc < 2; ++kc) {
    bf16x8 a[4];
#pragma unroll
    for (int ni = 0; ni < 4; ++ni) {
      int rn = wn * 64 + ni * 16 + l15;
      int ca = (kc * 4 + l4) ^ (rn & 7);
      a[ni] = *(const bf16x8*)(lA + (size_t)rn * 64 + ca * 8);
    }
#pragma unroll
    for (int mi = 0; mi < 8; ++mi) {
      int r = wm * 128 + mi * 16 + l15;
      int sc = (kc * 4 + l4) ^ (r & 7);
      bf16x8 b = *(const bf16x8*)((const char*)lB + (size_t)r * 128 + sc * 16);
#pragma unroll
      for (int ni = 0; ni < 4; ++ni)
        acc[ni][mi] = __builtin_amdgcn_mfma_f32_16x16x32_bf16(a[ni], b, acc[ni][mi], 0, 0, 0);
    }
  }
  __builtin_amdgcn_s_setprio(0);
}

// invariant entering body S: outstanding = [A4(S), B8(S+1), A4(S+1)] = 16
#define K3_BODY(S, RC, RI, DOISSUE)                                         \
  {                                                                         \
    K3_WAITV(4);                                                            \
    k3_writeB(lB[((S) + 1) & 1], rowB, cq, RC);                             \
    K3_LGKM0;                                                               \
    __builtin_amdgcn_s_barrier();                                           \
    k3_compute(lA[(S) & 1], lB[(S) & 1], acc, wm, wn, l15, l4);             \
    __builtin_amdgcn_s_barrier();                                           \
    if (DOISSUE) {                                                          \
      k3_loadB(adjp + ((S) + 2) * 64, RI);                                  \
      __builtin_amdgcn_sched_barrier(0);                                    \
      k3_issueA(aBase + (size_t)((S) + 2) * 16384, lA[(S) & 1], wave, lane);\
      __builtin_amdgcn_sched_barrier(0);                                    \
    }                                                                       \
  }

__global__ __launch_bounds__(512, 1)
void hgcn_k3(const float* __restrict__ adj, const u16* __restrict__ xtTp,
             float* __restrict__ pbase) {
  __shared__ u16 lA[2][256 * 64];  // 2 x 32KB (xtTp tiles, swizzle baked)
  __shared__ u16 lB[2][256 * 64];  // 2 x 32KB (adj bf16, XOR swizzle)
  int t = threadIdx.x;
  int wave = t >> 6, lane = t & 63;
  int l15 = lane & 15, l4 = lane >> 4;
  int wm = wave >> 2, wn = wave & 3;  // 2m x 4n waves; per wave 128m x 64n
  int bid = blockIdx.x;               // 256 = 32 mt x 8 split (split per XCD)
  int split = bid & 7;
  int mt = bid >> 3;
  int m0 = mt * 256;
  int kbase = split * KSZ;
  float* outp = pbase + (size_t)split * ((size_t)NROWS * DIM);

  int rowB = t >> 1, cq = t & 1;      // 256 rows x 2 threads, 128B each
  const float* adjp = adj + (size_t)(m0 + rowB) * KTOT + kbase + cq * 32;
  const u16* aBase = xtTp + (size_t)(split * 16) * 16384;

  f32x4 acc[4][8];
#pragma unroll
  for (int i = 0; i < 4; ++i)
#pragma unroll
    for (int j = 0; j < 8; ++j)
      acc[i][j] = (f32x4){0.f, 0.f, 0.f, 0.f};

  // prologue: FIFO = [B8(0), A4(0), B8(1), A4(1)] = 24
  B8 rA, rB;
  k3_loadB(adjp, rA);
  __builtin_amdgcn_sched_barrier(0);
  k3_issueA(aBase, lA[0], wave, lane);
  __builtin_amdgcn_sched_barrier(0);
  k3_loadB(adjp + 64, rB);
  __builtin_amdgcn_sched_barrier(0);
  k3_issueA(aBase + 16384, lA[1], wave, lane);
  __builtin_amdgcn_sched_barrier(0);
  K3_WAITV(16);                       // drain B8(0) -> invariant [A4(0),B8(1),A4(1)]
  k3_writeB(lB[0], rowB, cq, rA);

  for (int s = 0; s < 14; s += 2) {
    K3_BODY(s, rB, rA, true);
    K3_BODY(s + 1, rA, rB, true);
  }
  // body 14 (consume rB, no issue)
  K3_WAITV(4);
  k3_writeB(lB[1], rowB, cq, rB);
  K3_LGKM0;
  __builtin_amdgcn_s_barrier();
  k3_compute(lA[0], lB[0], acc, wm, wn, l15, l4);
  __builtin_amdgcn_s_barrier();
  // body 15
  K3_WAITV(0);
  __builtin_amdgcn_s_barrier();
  k3_compute(lA[1], lB[1], acc, wm, wn, l15, l4);

  // epilogue: D[n][m] -> partial[m][n]  (mapping verified r2-r11)
#pragma unroll
  for (int ni = 0; ni < 4; ++ni)
#pragma unroll
    for (int mi = 0; mi < 8; ++mi) {
      int n = wn * 64 + ni * 16 + l4 * 4;
      int m = m0 + wm * 128 + mi * 16 + l15;
      *(f32x4*)(outp + (size_t)m * DIM + n) = acc[ni][mi];
    }
}

// ---------------- K4: sum 8 partials + hyperbolic chain #2 -> d_out ----------------
__global__ __launch_bounds__(256)
void hgcn_k4(const float* __restrict__ pbase, size_t pstride,
             float* __restrict__ out) {
  const float maxn = 1.0f - 1e-5f;
  int t = threadIdx.x;
  int wave = t >> 6, lane = t & 63;
  size_t row = (size_t)blockIdx.x * 4 + wave;
  int c0 = lane * 4;
  size_t off = row * DIM + c0;
  float sx = 0.f, sy = 0.f, sz = 0.f, sw = 0.f;
#pragma unroll
  for (int i = 0; i < KSPLIT; ++i) {
    float4 v = *(const float4*)(pbase + (size_t)i * pstride + off);
    sx += v.x; sy += v.y; sz += v.z; sw += v.w;
  }
  float un2 = wsum(sx * sx + sy * sy + sz * sz + sw * sw);
  float un = fmaxf(sqrtf(un2), 1e-15f);
  float t1 = tanhf(un) / un;
  float hx = sx * t1, hy = sy * t1, hz = sz * t1, hw = sw * t1;
  float hn = fmaxf(fabsf(t1) * un, 1e-15f);
  float s1 = hn > maxn ? maxn / hn : 1.0f;
  hx *= s1; hy *= s1; hz *= s1; hw *= s1;
  float pn = fmaxf(hn * s1, 1e-15f);
  float lf = artanh_c(pn) / pn;
  float rx = fmaxf(hx * lf, 0.0f), ry = fmaxf(hy * lf, 0.0f);
  float rz = fmaxf(hz * lf, 0.0f), rw = fmaxf(hw * lf, 0.0f);
  float rn2 = wsum(rx * rx + ry * ry + rz * rz + rw * rw);
  float rn = fmaxf(sqrtf(rn2), 1e-15f);
  float t2 = tanhf(rn) / rn;
  float ox = rx * t2, oy = ry * t2, oz = rz * t2, ow = rw * t2;
  float on = fmaxf(fabsf(t2) * rn, 1e-15f);
  float s3 = on > maxn ? maxn / on : 1.0f;
  float4 o = {ox * s3, oy * s3, oz * s3, ow * s3};
  *(float4*)(out + off) = o;
}

extern "C" void kernel_launch(void* const* d_in, const int* in_sizes, int n_in,
                              void* d_out, int out_size, void* d_ws, size_t ws_size,
                              hipStream_t stream) {
  const float* x = (const float*)d_in[0];
  const float* adj = (const float*)d_in[1];
  const float* wgt = (const float*)d_in[2];
  const float* bias = (const float*)d_in[3];
  float* out = (float*)d_out;
  char* ws = (char*)d_ws;
  float* mx = (float*)ws;                           // [0, 8MB)
  u16* xtTp = (u16*)(ws + ((size_t)8 << 20));       // [8, 12MB)
  float* pbase = (float*)(ws + ((size_t)12 << 20)); // [12, 76MB): 8 partials x 8MB

  hipLaunchKernelGGL(hgcn_k1, dim3(128, 4), dim3(256), 0, stream, x, wgt, mx);
  hipLaunchKernelGGL(hgcn_k2, dim3(128), dim3(256), 0, stream, x, mx, bias, xtTp);
  hipLaunchKernelGGL(hgcn_k3, dim3(256), dim3(512), 0, stream, adj, xtTp, pbase);
  hipLaunchKernelGGL(hgcn_k4, dim3(2048), dim3(256), 0, stream,
                     pbase, (size_t)NROWS * DIM, out);
}